// Round 12
// baseline (255.091 us; speedup 1.0000x reference)
//
#include <hip/hip_runtime.h>
#include <math.h>

#define DIMC 64
#define DIN  128
#define LSEQ 9216
#define NPB  (DIMC*LSEQ)      // 589824 elements per batch
#define NCH  192              // scan chunks
#define CTL  48               // chunk length: NCH*CTL == LSEQ
#define NCHAIN 4096           // 2 batches * 128 d * 16 s
#define LOG2E 1.44269504088896340736f

__device__ __forceinline__ float siluf(float v)    { return v / (1.f + __expf(-v)); }
__device__ __forceinline__ float softplusf(float v){ return (v > 15.f) ? v : __logf(1.f + __expf(v)); }
__device__ __forceinline__ float clip10(float v)   { return fminf(10.f, fmaxf(-10.f, v)); }
__device__ __forceinline__ float getc(const float4 v, int k) {
  return (k == 0) ? v.x : (k == 1) ? v.y : (k == 2) ? v.z : v.w;
}

// ---------------- K1: per-batch sum/sumsq (blocks x<256) + weight prep (x>=256,y==0) ---
__global__ void k_init(const float* __restrict__ x, float* __restrict__ sums,
                       const float* __restrict__ W_in, const float* __restrict__ proj_w,
                       const float* __restrict__ W_out, const float* __restrict__ b_out,
                       const float* __restrict__ proj_b, const float* __restrict__ W_xproj,
                       const float* __restrict__ W_dt,
                       float* __restrict__ Wt, float* __restrict__ Mtp, float* __restrict__ bp,
                       float* __restrict__ Wbtd2, float* __restrict__ Wbc) {
  int bx = blockIdx.x, by = blockIdx.y;
  int t = threadIdx.x;
  if (bx < 256) {
    const float* xb = x + (size_t)by * NPB;
    float s = 0.f, s2 = 0.f;
    for (int i = bx * 256 + t; i < NPB; i += 65536) {
      float v = xb[i]; s += v; s2 = fmaf(v, v, s2);
    }
    __shared__ float l1[256], l2[256];
    l1[t] = s; l2[t] = s2; __syncthreads();
    for (int off = 128; off > 0; off >>= 1) {
      if (t < off) { l1[t] += l1[t + off]; l2[t] += l2[t + off]; }
      __syncthreads();
    }
    if (t == 0) { atomicAdd(&sums[2*by], l1[0]); atomicAdd(&sums[2*by+1], l2[0]); }
    return;
  }
  if (by != 0) return;
  int i = (bx - 256) * 256 + t;
  if (i < 16384) {                       // Wt[k*256+c] = W_in[c*64+k]
    int k = i >> 8, c = i & 255;
    Wt[i] = W_in[c * 64 + k];
    return;
  }
  int j = i - 16384;
  if (j < 8192) {                        // Mtp[(d*32+o32)*2+h] = (proj_w@W_out)[o][d]
    int d = j >> 6, o = j & 63, o32 = o & 31, h = o >> 5;
    float a = 0.f;
    for (int c = 0; c < 64; c++) a = fmaf(proj_w[o * 64 + c], W_out[c * DIN + d], a);
    Mtp[(d * 32 + o32) * 2 + h] = a;
    return;
  }
  int k2 = j - 8192;
  if (k2 < 64) {
    float a = proj_b[k2];
    for (int c = 0; c < 64; c++) a = fmaf(proj_w[k2 * 64 + c], b_out[c], a);
    bp[k2] = a;
    return;
  }
  int m = j - 8256;
  if (m < 16384) {                       // Wbtd2[(k*64+c)*2+h] = (W_dt@W_xproj[:4])[c+64h][k]
    int k = m >> 7, cc = m & 127, c = cc & 63, h = cc >> 6;
    float v = 0.f;
    #pragma unroll
    for (int r = 0; r < 4; r++) v = fmaf(W_dt[(c + 64 * h) * 4 + r], W_xproj[r * DIN + k], v);
    Wbtd2[(k * 64 + c) * 2 + h] = v;
    return;
  }
  int m2 = m - 16384;
  if (m2 < 4096) {                       // Wbc[k*32+j] = W_xproj[4+j][k]
    int k = m2 >> 5, jj = m2 & 31;
    Wbc[m2] = W_xproj[(4 + jj) * DIN + k];
  }
}

// ---------------- K2: normalize + clip; write res (B,C,L) and seq (B,L,C) ----------------
__global__ void k_norm(const float* __restrict__ x, const float* __restrict__ gam,
                       const float* __restrict__ bet, const float* __restrict__ sums,
                       float* __restrict__ seq, float* __restrict__ res) {
  int b = blockIdx.y, l0 = blockIdx.x * 64;
  float mean = sums[2*b] * (1.f / NPB);
  float var  = sums[2*b+1] * (1.f / NPB) - mean * mean;
  float inv  = rsqrtf(var + 1e-5f);
  __shared__ float tile[64][65];
  int t = threadIdx.x;
  int lr = t & 63, cg = t >> 6;
  #pragma unroll
  for (int i = 0; i < 16; i++) {
    int c = i * 4 + cg;
    size_t idx = ((size_t)(b * DIMC + c)) * LSEQ + l0 + lr;
    float v = x[idx];
    v = (v - mean) * inv * gam[c] + bet[c];
    v = clip10(v);
    res[idx] = v;
    tile[c][lr] = v;
  }
  __syncthreads();
  int cc = t & 63, lg = t >> 6;
  #pragma unroll
  for (int i = 0; i < 16; i++) {
    int l = i * 4 + lg;
    seq[((size_t)(b * LSEQ + l0 + l)) * DIMC + cc] = tile[cc][l];
  }
}

// ---------------- K3: fused in-proj GEMM + conv + SiLU + x-proj(dt/B/C) ----------------
// Phase 1: single col per thread (proven 52us config): 19-row window, LDS seq tile.
// Phase 2: xt LDS tile, wave-broadcast reads, col-pair weights.
__global__ void __launch_bounds__(256) k_mid(
    const float* __restrict__ seq, const float* __restrict__ Wt,
    const float* __restrict__ b_in, const float* __restrict__ conv_w,
    const float* __restrict__ conv_b, const float* __restrict__ Wbtd2,
    const float* __restrict__ Wbc, const float* __restrict__ b_dt,
    float* __restrict__ xs, float* __restrict__ zo, float* __restrict__ dt,
    float* __restrict__ Bm, float* __restrict__ Cm) {
  int row0 = blockIdx.x * 16;
  int l0 = row0 % LSEQ;                       // 0 only at a batch start
  int t = threadIdx.x;
  __shared__ float sq[19 * 64];               // seq rows row0-3 .. row0+15
  __shared__ float xt[16 * DIN];              // conv+silu outputs (x-tile)

  for (int i = t; i < 19 * 16; i += 256) {
    int r = i >> 4, k4 = i & 15;
    int rr = row0 - 3 + r; if (rr < 0) rr = 0;
    *(float4*)(sq + r * 64 + k4 * 4) = *(const float4*)(seq + (size_t)rr * DIMC + k4 * 4);
  }
  __syncthreads();

  // ---- Phase 1: in-proj + conv + silu (single col, 19-row window) ----
  {
    int c = t;
    float bi = b_in[c];
    float a[19];
    #pragma unroll
    for (int r = 0; r < 19; r++) a[r] = bi;
    const float4* sq4 = (const float4*)sq;
    #pragma unroll 4
    for (int k4 = 0; k4 < 16; k4++) {
      float w0 = Wt[(k4 * 4 + 0) * 256 + c];
      float w1 = Wt[(k4 * 4 + 1) * 256 + c];
      float w2 = Wt[(k4 * 4 + 2) * 256 + c];
      float w3 = Wt[(k4 * 4 + 3) * 256 + c];
      #pragma unroll
      for (int r = 0; r < 19; r++) {
        float4 v = sq4[r * 16 + k4];
        a[r] = fmaf(w0, v.x, a[r]);
        a[r] = fmaf(w1, v.y, a[r]);
        a[r] = fmaf(w2, v.z, a[r]);
        a[r] = fmaf(w3, v.w, a[r]);
      }
    }
    if (c < DIN) {
      if (l0 == 0) { a[0] = 0.f; a[1] = 0.f; a[2] = 0.f; }   // causal zero-pad
      float4 cw = *(const float4*)(conv_w + c * 4);
      float cb = conv_b[c];
      #pragma unroll
      for (int i2 = 0; i2 < 16; i2++) {
        float v = cb;
        v = fmaf(a[i2 + 0], cw.x, v);
        v = fmaf(a[i2 + 1], cw.y, v);
        v = fmaf(a[i2 + 2], cw.z, v);
        v = fmaf(a[i2 + 3], cw.w, v);
        float sv_ = siluf(v);
        xs[(size_t)(row0 + i2) * DIN + c] = sv_;
        xt[i2 * DIN + c] = sv_;
      }
    } else {
      int cz = c - DIN;
      #pragma unroll
      for (int i2 = 0; i2 < 16; i2++) zo[(size_t)(row0 + i2) * DIN + cz] = a[i2 + 3];
    }
  }
  __syncthreads();

  const float4* xt4 = (const float4*)xt;

  // ---- Phase 2a: dt composite, col-pair (cd, cd+64), 4 rows each ----
  {
    int cd = t & 63, rg = t >> 6;
    float acc0[4], acc1[4];
    float bd0 = b_dt[cd], bd1 = b_dt[cd + 64];
    #pragma unroll
    for (int r = 0; r < 4; r++) { acc0[r] = bd0; acc1[r] = bd1; }
    const float2* Wd2 = (const float2*)Wbtd2;
    for (int k4 = 0; k4 < 32; k4++) {
      float4 v0 = xt4[(rg * 4 + 0) * 32 + k4];
      float4 v1 = xt4[(rg * 4 + 1) * 32 + k4];
      float4 v2 = xt4[(rg * 4 + 2) * 32 + k4];
      float4 v3 = xt4[(rg * 4 + 3) * 32 + k4];
      #pragma unroll
      for (int kk = 0; kk < 4; kk++) {
        float2 w = Wd2[(size_t)(k4 * 4 + kk) * 64 + cd];
        float s0 = getc(v0, kk), s1 = getc(v1, kk), s2 = getc(v2, kk), s3 = getc(v3, kk);
        acc0[0] = fmaf(w.x, s0, acc0[0]); acc1[0] = fmaf(w.y, s0, acc1[0]);
        acc0[1] = fmaf(w.x, s1, acc0[1]); acc1[1] = fmaf(w.y, s1, acc1[1]);
        acc0[2] = fmaf(w.x, s2, acc0[2]); acc1[2] = fmaf(w.y, s2, acc1[2]);
        acc0[3] = fmaf(w.x, s3, acc0[3]); acc1[3] = fmaf(w.y, s3, acc1[3]);
      }
    }
    #pragma unroll
    for (int r = 0; r < 4; r++) {
      size_t ro = (size_t)(row0 + rg * 4 + r) * DIN;
      dt[ro + cd]      = softplusf(acc0[r]);
      dt[ro + cd + 64] = softplusf(acc1[r]);
    }
  }

  // ---- Phase 2b: B/C (32 cols), 2 rows each ----
  {
    int cb2 = t & 31, rg = t >> 5;
    float a0 = 0.f, a1 = 0.f;
    for (int k4 = 0; k4 < 32; k4++) {
      float4 v0 = xt4[(rg * 2 + 0) * 32 + k4];
      float4 v1 = xt4[(rg * 2 + 1) * 32 + k4];
      #pragma unroll
      for (int kk = 0; kk < 4; kk++) {
        float w = Wbc[(k4 * 4 + kk) * 32 + cb2];
        a0 = fmaf(w, getc(v0, kk), a0);
        a1 = fmaf(w, getc(v1, kk), a1);
      }
    }
    size_t r0 = (size_t)row0 + rg * 2;
    float* dst = (cb2 < 16) ? (Bm + r0 * 16 + cb2) : (Cm + r0 * 16 + (cb2 - 16));
    dst[0]  = a0;
    dst[16] = a1;
  }
}

// ---------------- K5a: scan chunk aggregates -------------------------------
// Lane layout d = t&127 (64 consecutive d per wave -> 256B coalesced dt/xs loads);
// q = t>>7 wave-uniform -> B loads are broadcast. No cross-q reduction needed here.
__global__ void __launch_bounds__(512) k_scanA(
    const float* __restrict__ dt, const float* __restrict__ Bmat,
    const float* __restrict__ xs, const float* __restrict__ A_log,
    float* __restrict__ Ap, float* __restrict__ Bg) {
  int chunk = blockIdx.x, b = blockIdx.y;
  int t = threadIdx.x;
  int d = t & 127, q = t >> 7;
  const float* al = A_log + d * 16 + q * 4;
  float a0 = -__expf(al[0]) * LOG2E, a1 = -__expf(al[1]) * LOG2E;
  float a2 = -__expf(al[2]) * LOG2E, a3 = -__expf(al[3]) * LOG2E;
  size_t base = (size_t)b * LSEQ + (size_t)chunk * CTL;
  const float* dtp = dt + base * DIN + d;
  const float* xsp = xs + base * DIN + d;
  const float4* bp4 = (const float4*)(Bmat + base * 16 + q * 4);
  float h0 = 0.f, h1 = 0.f, h2 = 0.f, h3 = 0.f;
  float p0 = 1.f, p1 = 1.f, p2 = 1.f, p3 = 1.f;
  #pragma unroll 4
  for (int i = 0; i < CTL; i++) {
    float dtv = dtp[(size_t)i * DIN];
    float xv  = xsp[(size_t)i * DIN];
    float4 bA = bp4[i * 4];
    float u = dtv * xv;
    float e;
    e = exp2f(dtv * a0); h0 = fmaf(e, h0, u * bA.x); p0 *= e;
    e = exp2f(dtv * a1); h1 = fmaf(e, h1, u * bA.y); p1 *= e;
    e = exp2f(dtv * a2); h2 = fmaf(e, h2, u * bA.z); p2 *= e;
    e = exp2f(dtv * a3); h3 = fmaf(e, h3, u * bA.w); p3 *= e;
  }
  size_t idx = (size_t)chunk * NCHAIN + (size_t)(b * DIN + d) * 16 + q * 4;
  *(float4*)(Ap + idx) = make_float4(p0, p1, p2, p3);
  *(float4*)(Bg + idx) = make_float4(h0, h1, h2, h3);
}

// ---------------- K5b: sequential combine across chunks ----------------
__global__ void k_scanB(const float* __restrict__ Ap, const float* __restrict__ Bg,
                        float* __restrict__ hinit) {
  int chain = blockIdx.x * 64 + threadIdx.x;   // 0..4095
  float h = 0.f;
  for (int c = 0; c < NCH; c++) {
    size_t idx = (size_t)c * NCHAIN + chain;
    hinit[idx] = h;
    h = fmaf(Ap[idx], h, Bg[idx]);
  }
}

// ---------------- K5c: re-scan + gate, then fused out-proj+BN+GELU+res+clip ------
__global__ void __launch_bounds__(512) k_scanC(
    const float* __restrict__ dt, const float* __restrict__ Bmat,
    const float* __restrict__ Cmat, const float* __restrict__ xs,
    const float* __restrict__ z, const float* __restrict__ A_log,
    const float* __restrict__ Dp, const float* __restrict__ hinit,
    const float* __restrict__ Mtp, const float* __restrict__ bp,
    const float* __restrict__ bn_g, const float* __restrict__ bn_bt,
    const float* __restrict__ bn_m, const float* __restrict__ bn_v,
    const float* __restrict__ res, float* __restrict__ out) {
  int chunk = blockIdx.x, b = blockIdx.y;
  int t = threadIdx.x;
  __shared__ float ytile[CTL * DIN];         // 24.6 KB
  __shared__ float trans[64 * 52];           // 13.3 KB
  {
    int d = t >> 2, q = t & 3;
    const float* al = A_log + d * 16 + q * 4;
    float a0 = -__expf(al[0]) * LOG2E, a1 = -__expf(al[1]) * LOG2E;
    float a2 = -__expf(al[2]) * LOG2E, a3 = -__expf(al[3]) * LOG2E;
    float dp = Dp[d];
    size_t base = (size_t)b * LSEQ + (size_t)chunk * CTL;
    const float* dtp = dt + base * DIN + d;
    const float* xsp = xs + base * DIN + d;
    const float* zp  = z  + base * DIN + d;
    const float4* bp4 = (const float4*)(Bmat + base * 16 + q * 4);
    const float4* cp4 = (const float4*)(Cmat + base * 16 + q * 4);
    size_t idx = (size_t)chunk * NCHAIN + (size_t)(b * DIN + d) * 16 + q * 4;
    float4 hv = *(const float4*)(hinit + idx);
    float h0 = hv.x, h1 = hv.y, h2 = hv.z, h3 = hv.w;
    #pragma unroll 2
    for (int i = 0; i < CTL; i++) {
      float dtv = dtp[(size_t)i * DIN];
      float xv  = xsp[(size_t)i * DIN];
      float4 bA = bp4[i * 4];
      float4 cA = cp4[i * 4];
      float u = dtv * xv;
      float e, p;
      e = exp2f(dtv * a0); h0 = fmaf(e, h0, u * bA.x); p = h0 * cA.x;
      e = exp2f(dtv * a1); h1 = fmaf(e, h1, u * bA.y); p = fmaf(h1, cA.y, p);
      e = exp2f(dtv * a2); h2 = fmaf(e, h2, u * bA.z); p = fmaf(h2, cA.z, p);
      e = exp2f(dtv * a3); h3 = fmaf(e, h3, u * bA.w); p = fmaf(h3, cA.w, p);
      p += __shfl_xor(p, 1);
      p += __shfl_xor(p, 2);
      if (q == 0) {
        float zv = zp[(size_t)i * DIN];
        ytile[i * DIN + d] = (p + xv * dp) * siluf(zv);
      }
    }
  }
  __syncthreads();

  // GEMM 48x128 @ Mtp -> 48x64, BN + GELU
  {
    int op = t & 31, rg = t >> 5;             // rg 0..15, 3 rows each
    float acc0[3], acc1[3];
    float b0 = bp[op], b1 = bp[op + 32];
    #pragma unroll
    for (int r = 0; r < 3; r++) { acc0[r] = b0; acc1[r] = b1; }
    const float4* yt4 = (const float4*)ytile;
    const float2* M2  = (const float2*)Mtp;
    for (int k4 = 0; k4 < 32; k4++) {
      float4 v0 = yt4[(rg * 3 + 0) * 32 + k4];
      float4 v1 = yt4[(rg * 3 + 1) * 32 + k4];
      float4 v2 = yt4[(rg * 3 + 2) * 32 + k4];
      #pragma unroll
      for (int kk = 0; kk < 4; kk++) {
        float2 w = M2[(size_t)(k4 * 4 + kk) * 32 + op];
        float s0 = getc(v0, kk), s1 = getc(v1, kk), s2 = getc(v2, kk);
        acc0[0] = fmaf(w.x, s0, acc0[0]); acc1[0] = fmaf(w.y, s0, acc1[0]);
        acc0[1] = fmaf(w.x, s1, acc0[1]); acc1[1] = fmaf(w.y, s1, acc1[1]);
        acc0[2] = fmaf(w.x, s2, acc0[2]); acc1[2] = fmaf(w.y, s2, acc1[2]);
      }
    }
    float g0 = bn_g[op], bt0 = bn_bt[op], mu0 = bn_m[op];
    float iv0 = rsqrtf(bn_v[op] + 1e-5f);
    float g1 = bn_g[op + 32], bt1 = bn_bt[op + 32], mu1 = bn_m[op + 32];
    float iv1 = rsqrtf(bn_v[op + 32] + 1e-5f);
    __syncthreads();          // ordering barrier (also tames epilogue scheduling / VGPR pressure)
    #pragma unroll
    for (int r = 0; r < 3; r++) {
      int row = rg * 3 + r;
      float a = (acc0[r] - mu0) * iv0 * g0 + bt0;
      a = 0.5f * a * (1.f + erff(a * 0.70710678118654752f));
      trans[op * 52 + row] = a;
      float a2 = (acc1[r] - mu1) * iv1 * g1 + bt1;
      a2 = 0.5f * a2 * (1.f + erff(a2 * 0.70710678118654752f));
      trans[(op + 32) * 52 + row] = a2;
    }
  }
  __syncthreads();

  // coalesced store: out[(b*64+c)*LSEQ + chunk*48 + l] with residual+clip
  int l0c = chunk * CTL;
  for (int task = t; task < 768; task += 512) {   // 64 c * 12 f4
    int c = task / 12, f = task - c * 12;
    float4 vv = *(const float4*)(trans + c * 52 + f * 4);
    size_t gi = ((size_t)(b * DIMC + c)) * LSEQ + l0c + f * 4;
    const float4 rv = *(const float4*)(res + gi);
    float4 o;
    o.x = clip10(rv.x + vv.x);
    o.y = clip10(rv.y + vv.y);
    o.z = clip10(rv.z + vv.z);
    o.w = clip10(rv.w + vv.w);
    *(float4*)(out + gi) = o;
  }
}

extern "C" void kernel_launch(void* const* d_in, const int* in_sizes, int n_in,
                              void* d_out, int out_size, void* d_ws, size_t ws_size,
                              hipStream_t stream) {
  const float* x       = (const float*)d_in[0];
  const float* gn_g    = (const float*)d_in[1];
  const float* gn_b    = (const float*)d_in[2];
  const float* W_in    = (const float*)d_in[3];
  const float* b_in    = (const float*)d_in[4];
  const float* conv_w  = (const float*)d_in[5];
  const float* conv_b  = (const float*)d_in[6];
  const float* W_xproj = (const float*)d_in[7];
  const float* W_dt    = (const float*)d_in[8];
  const float* b_dt    = (const float*)d_in[9];
  const float* A_log   = (const float*)d_in[10];
  const float* Dp      = (const float*)d_in[11];
  const float* W_out   = (const float*)d_in[12];
  const float* b_out   = (const float*)d_in[13];
  const float* proj_w  = (const float*)d_in[14];
  const float* proj_b  = (const float*)d_in[15];
  const float* bn_g    = (const float*)d_in[16];
  const float* bn_bt   = (const float*)d_in[17];
  const float* bn_m    = (const float*)d_in[18];
  const float* bn_v    = (const float*)d_in[19];

  float* ws = (float*)d_ws;
  float* sums = ws;                               // 64
  float* seq  = ws + 64;                          // 1179648 (B,L,C); dead after k_mid
  float* res  = seq + 1179648;                    // 1179648 (B,C,L)
  float* zbuf = res + 1179648;                    // 2359296
  float* xsb  = zbuf + 2359296;                   // 2359296
  float* dtb  = xsb + 2359296;                    // 2359296
  float* Bmb  = dtb + 2359296;                    // 294912
  float* Cmb  = Bmb + 294912;                     // 294912
  float* Wt   = Cmb + 294912;                     // 16384
  float* Mtp  = Wt + 16384;                       // 8192
  float* bp   = Mtp + 8192;                       // 64
  float* Wbtd2= bp + 64;                          // 16384
  float* Wbc  = Wbtd2 + 16384;                    // 4096
  float* Bgb  = Wbc + 4096;                       // 786432 (NCH*NCHAIN)
  float* hib  = Bgb + 786432;                     // 786432
  float* Apb  = seq;                              // 786432, reuses dead seq

  hipMemsetAsync(sums, 0, 64 * sizeof(float), stream);

  k_init<<<dim3(433, 2), 256, 0, stream>>>(x, sums, W_in, proj_w, W_out, b_out, proj_b,
                                           W_xproj, W_dt, Wt, Mtp, bp, Wbtd2, Wbc);
  k_norm<<<dim3(144, 2), 256, 0, stream>>>(x, gn_g, gn_b, sums, seq, res);
  k_mid<<<1152, 256, 0, stream>>>(seq, Wt, b_in, conv_w, conv_b, Wbtd2, Wbc, b_dt,
                                  xsb, zbuf, dtb, Bmb, Cmb);
  k_scanA<<<dim3(NCH, 2), 512, 0, stream>>>(dtb, Bmb, xsb, A_log, Apb, Bgb);
  k_scanB<<<64, 64, 0, stream>>>(Apb, Bgb, hib);
  k_scanC<<<dim3(NCH, 2), 512, 0, stream>>>(dtb, Bmb, Cmb, xsb, zbuf, A_log, Dp, hib,
                                            Mtp, bp, bn_g, bn_bt, bn_m, bn_v, res,
                                            (float*)d_out);
}

// Round 13
// 246.238 us; speedup vs baseline: 1.0359x; 1.0359x over previous
//
#include <hip/hip_runtime.h>
#include <math.h>

#define DIMC 64
#define DIN  128
#define LSEQ 9216
#define NPB  (DIMC*LSEQ)      // 589824 elements per batch
#define NCH  256              // scan chunks
#define CTL  36               // chunk length: NCH*CTL == LSEQ
#define NCHAIN 4096           // 2 batches * 128 d * 16 s
#define LOG2E 1.44269504088896340736f

__device__ __forceinline__ float siluf(float v)    { return v / (1.f + __expf(-v)); }
__device__ __forceinline__ float softplusf(float v){ return (v > 15.f) ? v : __logf(1.f + __expf(v)); }
__device__ __forceinline__ float clip10(float v)   { return fminf(10.f, fmaxf(-10.f, v)); }
__device__ __forceinline__ float getc(const float4 v, int k) {
  return (k == 0) ? v.x : (k == 1) ? v.y : (k == 2) ? v.z : v.w;
}

// ---------------- K1: per-batch sum/sumsq (blocks x<256) + weight prep (x>=256,y==0) ---
__global__ void k_init(const float* __restrict__ x, float* __restrict__ sums,
                       const float* __restrict__ W_in, const float* __restrict__ proj_w,
                       const float* __restrict__ W_out, const float* __restrict__ b_out,
                       const float* __restrict__ proj_b, const float* __restrict__ W_xproj,
                       const float* __restrict__ W_dt,
                       float* __restrict__ Wt, float* __restrict__ Mtp, float* __restrict__ bp,
                       float* __restrict__ Wbtd2, float* __restrict__ Wbc) {
  int bx = blockIdx.x, by = blockIdx.y;
  int t = threadIdx.x;
  if (bx < 256) {
    const float* xb = x + (size_t)by * NPB;
    float s = 0.f, s2 = 0.f;
    for (int i = bx * 256 + t; i < NPB; i += 65536) {
      float v = xb[i]; s += v; s2 = fmaf(v, v, s2);
    }
    __shared__ float l1[256], l2[256];
    l1[t] = s; l2[t] = s2; __syncthreads();
    for (int off = 128; off > 0; off >>= 1) {
      if (t < off) { l1[t] += l1[t + off]; l2[t] += l2[t + off]; }
      __syncthreads();
    }
    if (t == 0) { atomicAdd(&sums[2*by], l1[0]); atomicAdd(&sums[2*by+1], l2[0]); }
    return;
  }
  if (by != 0) return;
  int i = (bx - 256) * 256 + t;
  if (i < 16384) {                       // Wt[k*256+c] = W_in[c*64+k]
    int k = i >> 8, c = i & 255;
    Wt[i] = W_in[c * 64 + k];
    return;
  }
  int j = i - 16384;
  if (j < 8192) {                        // Mtp[(d*32+o32)*2+h] = (proj_w@W_out)[o][d]
    int d = j >> 6, o = j & 63, o32 = o & 31, h = o >> 5;
    float a = 0.f;
    for (int c = 0; c < 64; c++) a = fmaf(proj_w[o * 64 + c], W_out[c * DIN + d], a);
    Mtp[(d * 32 + o32) * 2 + h] = a;
    return;
  }
  int k2 = j - 8192;
  if (k2 < 64) {
    float a = proj_b[k2];
    for (int c = 0; c < 64; c++) a = fmaf(proj_w[k2 * 64 + c], b_out[c], a);
    bp[k2] = a;
    return;
  }
  int m = j - 8256;
  if (m < 16384) {                       // Wbtd2[(k*64+c)*2+h] = (W_dt@W_xproj[:4])[c+64h][k]
    int k = m >> 7, cc = m & 127, c = cc & 63, h = cc >> 6;
    float v = 0.f;
    #pragma unroll
    for (int r = 0; r < 4; r++) v = fmaf(W_dt[(c + 64 * h) * 4 + r], W_xproj[r * DIN + k], v);
    Wbtd2[(k * 64 + c) * 2 + h] = v;
    return;
  }
  int m2 = m - 16384;
  if (m2 < 4096) {                       // Wbc[k*32+j] = W_xproj[4+j][k]
    int k = m2 >> 5, jj = m2 & 31;
    Wbc[m2] = W_xproj[(4 + jj) * DIN + k];
  }
}

// ---------------- K2: normalize + clip; write res (B,C,L) and seq (B,L,C) ----------------
__global__ void k_norm(const float* __restrict__ x, const float* __restrict__ gam,
                       const float* __restrict__ bet, const float* __restrict__ sums,
                       float* __restrict__ seq, float* __restrict__ res) {
  int b = blockIdx.y, l0 = blockIdx.x * 64;
  float mean = sums[2*b] * (1.f / NPB);
  float var  = sums[2*b+1] * (1.f / NPB) - mean * mean;
  float inv  = rsqrtf(var + 1e-5f);
  __shared__ float tile[64][65];
  int t = threadIdx.x;
  int lr = t & 63, cg = t >> 6;
  #pragma unroll
  for (int i = 0; i < 16; i++) {
    int c = i * 4 + cg;
    size_t idx = ((size_t)(b * DIMC + c)) * LSEQ + l0 + lr;
    float v = x[idx];
    v = (v - mean) * inv * gam[c] + bet[c];
    v = clip10(v);
    res[idx] = v;
    tile[c][lr] = v;
  }
  __syncthreads();
  int cc = t & 63, lg = t >> 6;
  #pragma unroll
  for (int i = 0; i < 16; i++) {
    int l = i * 4 + lg;
    seq[((size_t)(b * LSEQ + l0 + l)) * DIMC + cc] = tile[cc][l];
  }
}

// ---------------- K3: fused in-proj GEMM + conv + SiLU + x-proj(dt/B/C) ----------------
__global__ void __launch_bounds__(256) k_mid(
    const float* __restrict__ seq, const float* __restrict__ Wt,
    const float* __restrict__ b_in, const float* __restrict__ conv_w,
    const float* __restrict__ conv_b, const float* __restrict__ Wbtd2,
    const float* __restrict__ Wbc, const float* __restrict__ b_dt,
    float* __restrict__ xs, float* __restrict__ zo, float* __restrict__ dt,
    float* __restrict__ Bm, float* __restrict__ Cm) {
  int row0 = blockIdx.x * 16;
  int l0 = row0 % LSEQ;                       // 0 only at a batch start
  int t = threadIdx.x;
  __shared__ float sq[19 * 64];               // seq rows row0-3 .. row0+15
  __shared__ float xt[16 * DIN];              // conv+silu outputs (x-tile)

  for (int i = t; i < 19 * 16; i += 256) {
    int r = i >> 4, k4 = i & 15;
    int rr = row0 - 3 + r; if (rr < 0) rr = 0;
    *(float4*)(sq + r * 64 + k4 * 4) = *(const float4*)(seq + (size_t)rr * DIMC + k4 * 4);
  }
  __syncthreads();

  // ---- Phase 1: in-proj + conv + silu (single col, 19-row window) ----
  {
    int c = t;
    float bi = b_in[c];
    float a[19];
    #pragma unroll
    for (int r = 0; r < 19; r++) a[r] = bi;
    const float4* sq4 = (const float4*)sq;
    #pragma unroll 4
    for (int k4 = 0; k4 < 16; k4++) {
      float w0 = Wt[(k4 * 4 + 0) * 256 + c];
      float w1 = Wt[(k4 * 4 + 1) * 256 + c];
      float w2 = Wt[(k4 * 4 + 2) * 256 + c];
      float w3 = Wt[(k4 * 4 + 3) * 256 + c];
      #pragma unroll
      for (int r = 0; r < 19; r++) {
        float4 v = sq4[r * 16 + k4];
        a[r] = fmaf(w0, v.x, a[r]);
        a[r] = fmaf(w1, v.y, a[r]);
        a[r] = fmaf(w2, v.z, a[r]);
        a[r] = fmaf(w3, v.w, a[r]);
      }
    }
    if (c < DIN) {
      if (l0 == 0) { a[0] = 0.f; a[1] = 0.f; a[2] = 0.f; }   // causal zero-pad
      float4 cw = *(const float4*)(conv_w + c * 4);
      float cb = conv_b[c];
      #pragma unroll
      for (int i2 = 0; i2 < 16; i2++) {
        float v = cb;
        v = fmaf(a[i2 + 0], cw.x, v);
        v = fmaf(a[i2 + 1], cw.y, v);
        v = fmaf(a[i2 + 2], cw.z, v);
        v = fmaf(a[i2 + 3], cw.w, v);
        float sv_ = siluf(v);
        xs[(size_t)(row0 + i2) * DIN + c] = sv_;
        xt[i2 * DIN + c] = sv_;
      }
    } else {
      int cz = c - DIN;
      #pragma unroll
      for (int i2 = 0; i2 < 16; i2++) zo[(size_t)(row0 + i2) * DIN + cz] = a[i2 + 3];
    }
  }
  __syncthreads();

  const float4* xt4 = (const float4*)xt;

  // ---- Phase 2a: dt composite, col-pair (cd, cd+64), 4 rows each ----
  {
    int cd = t & 63, rg = t >> 6;
    float acc0[4], acc1[4];
    float bd0 = b_dt[cd], bd1 = b_dt[cd + 64];
    #pragma unroll
    for (int r = 0; r < 4; r++) { acc0[r] = bd0; acc1[r] = bd1; }
    const float2* Wd2 = (const float2*)Wbtd2;
    for (int k4 = 0; k4 < 32; k4++) {
      float4 v0 = xt4[(rg * 4 + 0) * 32 + k4];
      float4 v1 = xt4[(rg * 4 + 1) * 32 + k4];
      float4 v2 = xt4[(rg * 4 + 2) * 32 + k4];
      float4 v3 = xt4[(rg * 4 + 3) * 32 + k4];
      #pragma unroll
      for (int kk = 0; kk < 4; kk++) {
        float2 w = Wd2[(size_t)(k4 * 4 + kk) * 64 + cd];
        float s0 = getc(v0, kk), s1 = getc(v1, kk), s2 = getc(v2, kk), s3 = getc(v3, kk);
        acc0[0] = fmaf(w.x, s0, acc0[0]); acc1[0] = fmaf(w.y, s0, acc1[0]);
        acc0[1] = fmaf(w.x, s1, acc0[1]); acc1[1] = fmaf(w.y, s1, acc1[1]);
        acc0[2] = fmaf(w.x, s2, acc0[2]); acc1[2] = fmaf(w.y, s2, acc1[2]);
        acc0[3] = fmaf(w.x, s3, acc0[3]); acc1[3] = fmaf(w.y, s3, acc1[3]);
      }
    }
    #pragma unroll
    for (int r = 0; r < 4; r++) {
      size_t ro = (size_t)(row0 + rg * 4 + r) * DIN;
      dt[ro + cd]      = softplusf(acc0[r]);
      dt[ro + cd + 64] = softplusf(acc1[r]);
    }
  }

  // ---- Phase 2b: B/C (32 cols), 2 rows each ----
  {
    int cb2 = t & 31, rg = t >> 5;
    float a0 = 0.f, a1 = 0.f;
    for (int k4 = 0; k4 < 32; k4++) {
      float4 v0 = xt4[(rg * 2 + 0) * 32 + k4];
      float4 v1 = xt4[(rg * 2 + 1) * 32 + k4];
      #pragma unroll
      for (int kk = 0; kk < 4; kk++) {
        float w = Wbc[(k4 * 4 + kk) * 32 + cb2];
        a0 = fmaf(w, getc(v0, kk), a0);
        a1 = fmaf(w, getc(v1, kk), a1);
      }
    }
    size_t r0 = (size_t)row0 + rg * 2;
    float* dst = (cb2 < 16) ? (Bm + r0 * 16 + cb2) : (Cm + r0 * 16 + (cb2 - 16));
    dst[0]  = a0;
    dst[16] = a1;
  }
}

// ---------------- K5a: scan chunk aggregates (proven d=t>>2 mapping) -------------
__global__ void __launch_bounds__(512) k_scanA(
    const float* __restrict__ dt, const float* __restrict__ Bmat,
    const float* __restrict__ xs, const float* __restrict__ A_log,
    float* __restrict__ Ap, float* __restrict__ Bg) {
  int chunk = blockIdx.x, b = blockIdx.y;
  int t = threadIdx.x;
  int d = t >> 2, q = t & 3;
  const float* al = A_log + d * 16 + q * 4;
  float a0 = -__expf(al[0]) * LOG2E, a1 = -__expf(al[1]) * LOG2E;
  float a2 = -__expf(al[2]) * LOG2E, a3 = -__expf(al[3]) * LOG2E;
  size_t base = (size_t)b * LSEQ + (size_t)chunk * CTL;
  const float* dtp = dt + base * DIN + d;
  const float* xsp = xs + base * DIN + d;
  const float4* bp4 = (const float4*)(Bmat + base * 16 + q * 4);
  float h0 = 0.f, h1 = 0.f, h2 = 0.f, h3 = 0.f;
  float p0 = 1.f, p1 = 1.f, p2 = 1.f, p3 = 1.f;
  #pragma unroll 4
  for (int i = 0; i < CTL; i++) {
    float dtv = dtp[(size_t)i * DIN];
    float xv  = xsp[(size_t)i * DIN];
    float4 bA = bp4[i * 4];
    float u = dtv * xv;
    float e;
    e = exp2f(dtv * a0); h0 = fmaf(e, h0, u * bA.x); p0 *= e;
    e = exp2f(dtv * a1); h1 = fmaf(e, h1, u * bA.y); p1 *= e;
    e = exp2f(dtv * a2); h2 = fmaf(e, h2, u * bA.z); p2 *= e;
    e = exp2f(dtv * a3); h3 = fmaf(e, h3, u * bA.w); p3 *= e;
  }
  size_t idx = (size_t)chunk * NCHAIN + (size_t)(b * DIN + d) * 16 + q * 4;
  *(float4*)(Ap + idx) = make_float4(p0, p1, p2, p3);
  *(float4*)(Bg + idx) = make_float4(h0, h1, h2, h3);
}

// ---------------- K5b: sequential combine across chunks ----------------
__global__ void k_scanB(const float* __restrict__ Ap, const float* __restrict__ Bg,
                        float* __restrict__ hinit) {
  int chain = blockIdx.x * 64 + threadIdx.x;   // 0..4095
  float h = 0.f;
  for (int c = 0; c < NCH; c++) {
    size_t idx = (size_t)c * NCHAIN + chain;
    hinit[idx] = h;
    h = fmaf(Ap[idx], h, Bg[idx]);
  }
}

// ---------------- K5c: re-scan + gate, then fused out-proj+BN+GELU+res+clip ------
__global__ void __launch_bounds__(512) k_scanC(
    const float* __restrict__ dt, const float* __restrict__ Bmat,
    const float* __restrict__ Cmat, const float* __restrict__ xs,
    const float* __restrict__ z, const float* __restrict__ A_log,
    const float* __restrict__ Dp, const float* __restrict__ hinit,
    const float* __restrict__ Mtp, const float* __restrict__ bp,
    const float* __restrict__ bn_g, const float* __restrict__ bn_bt,
    const float* __restrict__ bn_m, const float* __restrict__ bn_v,
    const float* __restrict__ res, float* __restrict__ out) {
  int chunk = blockIdx.x, b = blockIdx.y;
  int t = threadIdx.x;
  __shared__ float ytile[CTL * DIN];         // 18.4 KB
  __shared__ float trans[64 * CTL];          // 9.2 KB, [c][row], stride 36 (16B-aligned f4 reads)
  {
    int d = t >> 2, q = t & 3;
    const float* al = A_log + d * 16 + q * 4;
    float a0 = -__expf(al[0]) * LOG2E, a1 = -__expf(al[1]) * LOG2E;
    float a2 = -__expf(al[2]) * LOG2E, a3 = -__expf(al[3]) * LOG2E;
    float dp = Dp[d];
    size_t base = (size_t)b * LSEQ + (size_t)chunk * CTL;
    const float* dtp = dt + base * DIN + d;
    const float* xsp = xs + base * DIN + d;
    const float* zp  = z  + base * DIN + d;
    const float4* bp4 = (const float4*)(Bmat + base * 16 + q * 4);
    const float4* cp4 = (const float4*)(Cmat + base * 16 + q * 4);
    size_t idx = (size_t)chunk * NCHAIN + (size_t)(b * DIN + d) * 16 + q * 4;
    float4 hv = *(const float4*)(hinit + idx);
    float h0 = hv.x, h1 = hv.y, h2 = hv.z, h3 = hv.w;
    #pragma unroll 2
    for (int i = 0; i < CTL; i++) {
      float dtv = dtp[(size_t)i * DIN];
      float xv  = xsp[(size_t)i * DIN];
      float4 bA = bp4[i * 4];
      float4 cA = cp4[i * 4];
      float u = dtv * xv;
      float e, p;
      e = exp2f(dtv * a0); h0 = fmaf(e, h0, u * bA.x); p = h0 * cA.x;
      e = exp2f(dtv * a1); h1 = fmaf(e, h1, u * bA.y); p = fmaf(h1, cA.y, p);
      e = exp2f(dtv * a2); h2 = fmaf(e, h2, u * bA.z); p = fmaf(h2, cA.z, p);
      e = exp2f(dtv * a3); h3 = fmaf(e, h3, u * bA.w); p = fmaf(h3, cA.w, p);
      p += __shfl_xor(p, 1);
      p += __shfl_xor(p, 2);
      if (q == 0) {
        float zv = zp[(size_t)i * DIN];
        ytile[i * DIN + d] = (p + xv * dp) * siluf(zv);
      }
    }
  }
  __syncthreads();

  // GEMM 36x128 @ Mtp -> 36x64, BN + GELU (12 active row-groups x 3 rows)
  {
    int op = t & 31, rg = t >> 5;             // rg 0..15; groups >=12 idle
    bool act = (rg < 12);
    float acc0[3], acc1[3];
    float b0 = bp[op], b1 = bp[op + 32];
    #pragma unroll
    for (int r = 0; r < 3; r++) { acc0[r] = b0; acc1[r] = b1; }
    if (act) {
      const float4* yt4 = (const float4*)ytile;
      const float2* M2  = (const float2*)Mtp;
      for (int k4 = 0; k4 < 32; k4++) {
        float4 v0 = yt4[(rg * 3 + 0) * 32 + k4];
        float4 v1 = yt4[(rg * 3 + 1) * 32 + k4];
        float4 v2 = yt4[(rg * 3 + 2) * 32 + k4];
        #pragma unroll
        for (int kk = 0; kk < 4; kk++) {
          float2 w = M2[(size_t)(k4 * 4 + kk) * 32 + op];
          float s0 = getc(v0, kk), s1 = getc(v1, kk), s2 = getc(v2, kk);
          acc0[0] = fmaf(w.x, s0, acc0[0]); acc1[0] = fmaf(w.y, s0, acc1[0]);
          acc0[1] = fmaf(w.x, s1, acc0[1]); acc1[1] = fmaf(w.y, s1, acc1[1]);
          acc0[2] = fmaf(w.x, s2, acc0[2]); acc1[2] = fmaf(w.y, s2, acc1[2]);
        }
      }
    }
    float g0 = bn_g[op], bt0 = bn_bt[op], mu0 = bn_m[op];
    float iv0 = rsqrtf(bn_v[op] + 1e-5f);
    float g1 = bn_g[op + 32], bt1 = bn_bt[op + 32], mu1 = bn_m[op + 32];
    float iv1 = rsqrtf(bn_v[op + 32] + 1e-5f);
    __syncthreads();          // ordering barrier (tames epilogue scheduling / VGPR pressure)
    if (act) {
      #pragma unroll
      for (int r = 0; r < 3; r++) {
        int row = rg * 3 + r;
        float a = (acc0[r] - mu0) * iv0 * g0 + bt0;
        a = 0.5f * a * (1.f + erff(a * 0.70710678118654752f));
        trans[op * CTL + row] = a;
        float a2 = (acc1[r] - mu1) * iv1 * g1 + bt1;
        a2 = 0.5f * a2 * (1.f + erff(a2 * 0.70710678118654752f));
        trans[(op + 32) * CTL + row] = a2;
      }
    }
  }
  __syncthreads();

  // coalesced store: out[(b*64+c)*LSEQ + chunk*36 + l] with residual+clip
  int l0c = chunk * CTL;
  for (int task = t; task < 576; task += 512) {   // 64 c * 9 f4
    int c = task / 9, f = task - c * 9;
    float4 vv = *(const float4*)(trans + c * CTL + f * 4);
    size_t gi = ((size_t)(b * DIMC + c)) * LSEQ + l0c + f * 4;
    const float4 rv = *(const float4*)(res + gi);
    float4 o;
    o.x = clip10(rv.x + vv.x);
    o.y = clip10(rv.y + vv.y);
    o.z = clip10(rv.z + vv.z);
    o.w = clip10(rv.w + vv.w);
    *(float4*)(out + gi) = o;
  }
}

extern "C" void kernel_launch(void* const* d_in, const int* in_sizes, int n_in,
                              void* d_out, int out_size, void* d_ws, size_t ws_size,
                              hipStream_t stream) {
  const float* x       = (const float*)d_in[0];
  const float* gn_g    = (const float*)d_in[1];
  const float* gn_b    = (const float*)d_in[2];
  const float* W_in    = (const float*)d_in[3];
  const float* b_in    = (const float*)d_in[4];
  const float* conv_w  = (const float*)d_in[5];
  const float* conv_b  = (const float*)d_in[6];
  const float* W_xproj = (const float*)d_in[7];
  const float* W_dt    = (const float*)d_in[8];
  const float* b_dt    = (const float*)d_in[9];
  const float* A_log   = (const float*)d_in[10];
  const float* Dp      = (const float*)d_in[11];
  const float* W_out   = (const float*)d_in[12];
  const float* b_out   = (const float*)d_in[13];
  const float* proj_w  = (const float*)d_in[14];
  const float* proj_b  = (const float*)d_in[15];
  const float* bn_g    = (const float*)d_in[16];
  const float* bn_bt   = (const float*)d_in[17];
  const float* bn_m    = (const float*)d_in[18];
  const float* bn_v    = (const float*)d_in[19];

  float* ws = (float*)d_ws;
  float* sums = ws;                               // 64
  float* seq  = ws + 64;                          // 1179648 (B,L,C); dead after k_mid
  float* res  = seq + 1179648;                    // 1179648 (B,C,L)
  float* zbuf = res + 1179648;                    // 2359296
  float* xsb  = zbuf + 2359296;                   // 2359296
  float* dtb  = xsb + 2359296;                    // 2359296
  float* Bmb  = dtb + 2359296;                    // 294912
  float* Cmb  = Bmb + 294912;                     // 294912
  float* Wt   = Cmb + 294912;                     // 16384
  float* Mtp  = Wt + 16384;                       // 8192
  float* bp   = Mtp + 8192;                       // 64
  float* Wbtd2= bp + 64;                          // 16384
  float* Wbc  = Wbtd2 + 16384;                    // 4096
  float* Bgb  = Wbc + 4096;                       // 1048576 (NCH*NCHAIN)
  float* hib  = Bgb + 1048576;                    // 1048576
  float* Apb  = seq;                              // 1048576, reuses dead seq

  hipMemsetAsync(sums, 0, 64 * sizeof(float), stream);

  k_init<<<dim3(433, 2), 256, 0, stream>>>(x, sums, W_in, proj_w, W_out, b_out, proj_b,
                                           W_xproj, W_dt, Wt, Mtp, bp, Wbtd2, Wbc);
  k_norm<<<dim3(144, 2), 256, 0, stream>>>(x, gn_g, gn_b, sums, seq, res);
  k_mid<<<1152, 256, 0, stream>>>(seq, Wt, b_in, conv_w, conv_b, Wbtd2, Wbc, b_dt,
                                  xsb, zbuf, dtb, Bmb, Cmb);
  k_scanA<<<dim3(NCH, 2), 512, 0, stream>>>(dtb, Bmb, xsb, A_log, Apb, Bgb);
  k_scanB<<<64, 64, 0, stream>>>(Apb, Bgb, hib);
  k_scanC<<<dim3(NCH, 2), 512, 0, stream>>>(dtb, Bmb, Cmb, xsb, zbuf, A_log, Dp, hib,
                                            Mtp, bp, bn_g, bn_bt, bn_m, bn_v, res,
                                            (float*)d_out);
}